// Round 4
// baseline (376.404 us; speedup 1.0000x reference)
//
#include <hip/hip_runtime.h>

typedef unsigned int u32;
typedef unsigned short u16;
typedef __bf16 bf16x8 __attribute__((ext_vector_type(8)));
typedef float f32x4 __attribute__((ext_vector_type(4)));

#define NREP 8   // histogram replicas

__device__ __forceinline__ u16 f2bf(float f) {
  u32 u = __builtin_bit_cast(u32, f);
  u32 r = (u + 0x7fffu + ((u >> 16) & 1u)) >> 16;   // RTNE
  return (u16)r;
}
__device__ __forceinline__ float bfhi(u32 w) { return __builtin_bit_cast(float, w & 0xffff0000u); }
__device__ __forceinline__ float bflo(u32 w) { return __builtin_bit_cast(float, w << 16); }

// ---------------- fused pre-pass: convx | zero count8 | convw ----------------
__global__ __launch_bounds__(256) void pre_k(const float* __restrict__ x, u16* __restrict__ comb,
                                             const float* __restrict__ W, u16* __restrict__ wbf,
                                             u32* __restrict__ count, int N, int nbx, int nbz) {
  int b = blockIdx.x, tid = threadIdx.x;
  if (b < nbx) {                       // x (N x 128 f32) -> comb[:,0:128] bf16 (row stride 256)
    int i = b * 256 + tid;
    if (i < N * 32) {
      size_t base = (size_t)i * 4;
      size_t row = base >> 7;
      int col = (int)(base & 127);
      const float4 v = *(const float4*)(x + base);
      ushort4 o = { f2bf(v.x), f2bf(v.y), f2bf(v.z), f2bf(v.w) };
      *(ushort4*)(comb + (row << 8) + col) = o;
    }
  } else if (b < nbx + nbz) {          // zero the replicated count array (NREP*N)
    int i = (b - nbx) * 256 + tid;
    if (i < NREP * N) count[i] = 0u;
  } else {                             // W (128 x 256 f32) -> bf16
    int i = (b - nbx - nbz) * 256 + tid;
    if (i < 8192) {
      const float4 v = *(const float4*)(W + (size_t)i * 4);
      ushort4 o = { f2bf(v.x), f2bf(v.y), f2bf(v.z), f2bf(v.w) };
      *(ushort4*)(wbf + (size_t)i * 4) = o;
    }
  }
}

// ---------------- count + local rank (replicated: replica = block % 8) ----------------
__global__ void count_k(const int* __restrict__ dst, int E, int N, u32* __restrict__ count,
                        u32* __restrict__ lpos) {
  int i = blockIdx.x * blockDim.x + threadIdx.x;
  if (i < E) {
    int r = (i >> 8) & (NREP - 1);
    lpos[i] = atomicAdd(&count[(size_t)r * N + dst[i]], 1u);
  }
}

// phase 1: per-block (1024-wide) exclusive scan over (d-major, r-minor) view of count[r][N]
__global__ __launch_bounds__(1024) void scan1_k(const u32* __restrict__ count, int N,
                                                u32* __restrict__ offsets, u32* __restrict__ partials) {
  __shared__ u32 s[1024];
  int tid = threadIdx.x;
  int i = blockIdx.x * 1024 + tid;
  int ntot = NREP * N;
  u32 v = (i < ntot) ? count[(size_t)(i & (NREP - 1)) * N + (i >> 3)] : 0u;
  s[tid] = v;
  __syncthreads();
  for (int off = 1; off < 1024; off <<= 1) {
    u32 t = (tid >= off) ? s[tid - off] : 0u;
    __syncthreads();
    s[tid] += t;
    __syncthreads();
  }
  offsets[i] = s[tid] - v;             // block-local exclusive (padding gets block total)
  if (tid == 1023) partials[blockIdx.x] = s[1023];
}

// phase 2: one block scans the partials (NB <= 1024) -> exclusive block bases
__global__ __launch_bounds__(1024) void scan2_k(u32* __restrict__ partials, int NB) {
  __shared__ u32 s[1024];
  int tid = threadIdx.x;
  u32 v = (tid < NB) ? partials[tid] : 0u;
  s[tid] = v;
  __syncthreads();
  for (int off = 1; off < 1024; off <<= 1) {
    u32 t = (tid >= off) ? s[tid - off] : 0u;
    __syncthreads();
    s[tid] += t;
    __syncthreads();
  }
  if (tid < NB) partials[tid] = s[tid] - v;
  if (tid == 1023) partials[NB] = s[1023];
}

// ---------------- scatter (no atomics) ----------------
__global__ void scatter_k(const int* __restrict__ src, const int* __restrict__ dst, int E,
                          const u32* __restrict__ offsets, const u32* __restrict__ partials,
                          const u32* __restrict__ lpos, int* __restrict__ ssrc) {
  int i = blockIdx.x * blockDim.x + threadIdx.x;
  if (i < E) {
    int d = dst[i];
    int r = (i >> 8) & (NREP - 1);
    u32 slot = (u32)d * NREP + r;
    u32 pos = offsets[slot] + partials[slot >> 10] + lpos[i];
    ssrc[pos] = src[i];
  }
}

// ---------------- aggregate: one wave per node, 8 edges in flight ----------------
__global__ __launch_bounds__(256) void agg_k(const int* __restrict__ ssrc,
                                             const u32* __restrict__ offsets,
                                             const u32* __restrict__ partials,
                                             u16* comb, int N) {
  int wid = (blockIdx.x * blockDim.x + threadIdx.x) >> 6;
  int lane = threadIdx.x & 63;
  if (wid >= N) return;
  int sub = lane >> 4;
  int cl = lane & 15;
  u32 slot0 = (u32)wid * NREP;
  u32 slot1 = (u32)(wid + 1) * NREP;
  u32 s0 = offsets[slot0] + partials[slot0 >> 10];
  u32 s1 = offsets[slot1] + partials[slot1 >> 10];
  float a0=0.f,a1=0.f,a2=0.f,a3=0.f,a4=0.f,a5=0.f,a6=0.f,a7=0.f;
  u32 j = s0 + sub;
  for (; j + 4 < s1; j += 8) {
    int sA = ssrc[j];
    int sB = ssrc[j + 4];
    uint4 vA = *(const uint4*)(comb + ((size_t)sA << 8) + (cl << 3));
    uint4 vB = *(const uint4*)(comb + ((size_t)sB << 8) + (cl << 3));
    a0 += bflo(vA.x); a1 += bfhi(vA.x);
    a2 += bflo(vA.y); a3 += bfhi(vA.y);
    a4 += bflo(vA.z); a5 += bfhi(vA.z);
    a6 += bflo(vA.w); a7 += bfhi(vA.w);
    a0 += bflo(vB.x); a1 += bfhi(vB.x);
    a2 += bflo(vB.y); a3 += bfhi(vB.y);
    a4 += bflo(vB.z); a5 += bfhi(vB.z);
    a6 += bflo(vB.w); a7 += bfhi(vB.w);
  }
  if (j < s1) {
    int s = ssrc[j];
    uint4 v = *(const uint4*)(comb + ((size_t)s << 8) + (cl << 3));
    a0 += bflo(v.x); a1 += bfhi(v.x);
    a2 += bflo(v.y); a3 += bfhi(v.y);
    a4 += bflo(v.z); a5 += bfhi(v.z);
    a6 += bflo(v.w); a7 += bfhi(v.w);
  }
  a0 += __shfl_xor(a0, 16); a1 += __shfl_xor(a1, 16);
  a2 += __shfl_xor(a2, 16); a3 += __shfl_xor(a3, 16);
  a4 += __shfl_xor(a4, 16); a5 += __shfl_xor(a5, 16);
  a6 += __shfl_xor(a6, 16); a7 += __shfl_xor(a7, 16);
  a0 += __shfl_xor(a0, 32); a1 += __shfl_xor(a1, 32);
  a2 += __shfl_xor(a2, 32); a3 += __shfl_xor(a3, 32);
  a4 += __shfl_xor(a4, 32); a5 += __shfl_xor(a5, 32);
  a6 += __shfl_xor(a6, 32); a7 += __shfl_xor(a7, 32);
  if (sub == 0) {
    u32 deg = s1 - s0;
    float inv = 1.0f / (float)(deg > 0u ? deg : 1u);
    uint4 o;
    o.x = (u32)f2bf(a0 * inv) | ((u32)f2bf(a1 * inv) << 16);
    o.y = (u32)f2bf(a2 * inv) | ((u32)f2bf(a3 * inv) << 16);
    o.z = (u32)f2bf(a4 * inv) | ((u32)f2bf(a5 * inv) << 16);
    o.w = (u32)f2bf(a6 * inv) | ((u32)f2bf(a7 * inv) << 16);
    *(uint4*)(comb + ((size_t)wid << 8) + 128 + (cl << 3)) = o;
  }
}

// ---------------- GEMM: comb (N x 256 bf16) @ Wbf^T (+bias) -> out (N x 128 f32) ----------------
__global__ __launch_bounds__(256) void gemm_k(const u16* __restrict__ comb,
                                              const u16* __restrict__ wbf,
                                              const float* __restrict__ bias,
                                              float* __restrict__ out, int nstrips) {
  int wave = threadIdx.x >> 6, lane = threadIdx.x & 63;
  int strip = blockIdx.x * 4 + wave;
  if (strip >= nstrips) return;
  int la = lane & 15, lb = lane >> 4;

  const u16* abase = comb + ((size_t)(strip * 16 + la) << 8) + lb * 8;
  bf16x8 a[8];
#pragma unroll
  for (int kb = 0; kb < 8; kb++) a[kb] = *(const bf16x8*)(abase + kb * 32);

#pragma unroll
  for (int ct = 0; ct < 8; ct++) {
    f32x4 acc = { 0.f, 0.f, 0.f, 0.f };
    const u16* bbase = wbf + ((size_t)(ct * 16 + la) << 8) + lb * 8;
#pragma unroll
    for (int kb = 0; kb < 8; kb++) {
      bf16x8 b = *(const bf16x8*)(bbase + kb * 32);
      acc = __builtin_amdgcn_mfma_f32_16x16x32_bf16(a[kb], b, acc, 0, 0, 0);
    }
    float bc = bias[ct * 16 + la];
    int r0 = strip * 16 + lb * 4;
#pragma unroll
    for (int j = 0; j < 4; j++)
      out[((size_t)(r0 + j) << 7) + ct * 16 + la] = acc[j] + bc;
  }
}

extern "C" void kernel_launch(void* const* d_in, const int* in_sizes, int n_in,
                              void* d_out, int out_size, void* d_ws, size_t ws_size,
                              hipStream_t stream) {
  const float* x    = (const float*)d_in[0];
  const int*   ei   = (const int*)d_in[1];
  const float* W    = (const float*)d_in[2];
  const float* bias = (const float*)d_in[3];
  const int N = in_sizes[0] / 128;
  const int E = in_sizes[1] / 2;
  const int NTOT = NREP * N;                 // replicated counter slots
  const int NB = (NTOT + 1023) / 1024;       // scan blocks (<=1024)
  const int* src = ei;
  const int* dst = ei + E;
  float* out = (float*)d_out;

  // CSR-build scratch lives in d_out (dead before gemm_k overwrites it):
  //   lpos[E] | count8[NREP*N] | offsets8[NB*1024] | partials[NB+1]
  u32* lpos     = (u32*)d_out;               // E
  u32* count8   = lpos + E;                  // NREP*N
  u32* offsets8 = count8 + NTOT;             // NB*1024 (padded)
  u32* partials = offsets8 + (size_t)NB * 1024;  // NB+1

  char* ws = (char*)d_ws;
  int* ssrc = (int*)ws;                      // E
  size_t off = ((size_t)E * 4 + 255) & ~(size_t)255;
  u16* comb = (u16*)(ws + off);              // N*256 bf16 (x | mean)
  u16* wbf  = comb + (size_t)N * 256;        // 128*256 bf16

  const int nbx = (N * 32 + 255) / 256;
  const int nbz = (NTOT + 255) / 256;
  pre_k<<<nbx + nbz + 32, 256, 0, stream>>>(x, comb, W, wbf, count8, N, nbx, nbz);
  count_k<<<(E + 255) / 256, 256, 0, stream>>>(dst, E, N, count8, lpos);
  scan1_k<<<NB, 1024, 0, stream>>>(count8, N, offsets8, partials);
  scan2_k<<<1, 1024, 0, stream>>>(partials, NB);
  scatter_k<<<(E + 255) / 256, 256, 0, stream>>>(src, dst, E, offsets8, partials, lpos, ssrc);
  agg_k<<<(N + 3) / 4, 256, 0, stream>>>(ssrc, offsets8, partials, comb, N);
  gemm_k<<<(N / 16 + 3) / 4, 256, 0, stream>>>(comb, wbf, bias, out, N / 16);
}

// Round 5
// 283.776 us; speedup vs baseline: 1.3264x; 1.3264x over previous
//
#include <hip/hip_runtime.h>

typedef unsigned int u32;
typedef unsigned short u16;
typedef __bf16 bf16x8 __attribute__((ext_vector_type(8)));
typedef float f32x4 __attribute__((ext_vector_type(4)));

__device__ __forceinline__ u16 f2bf(float f) {
  u32 u = __builtin_bit_cast(u32, f);
  u32 r = (u + 0x7fffu + ((u >> 16) & 1u)) >> 16;   // RTNE
  return (u16)r;
}
__device__ __forceinline__ float bfhi(u32 w) { return __builtin_bit_cast(float, w & 0xffff0000u); }
__device__ __forceinline__ float bflo(u32 w) { return __builtin_bit_cast(float, w << 16); }

// ---------------- fused pre-pass: convx | zero bktTotal | convw ----------------
__global__ __launch_bounds__(256) void pre_k(const float* __restrict__ x, u16* __restrict__ comb,
                                             const float* __restrict__ W, u16* __restrict__ wbf,
                                             u32* __restrict__ bktTotal, int N, int nbkt,
                                             int nbx, int nbz) {
  int b = blockIdx.x, tid = threadIdx.x;
  if (b < nbx) {                       // x (N x 128 f32) -> comb[:,0:128] bf16 (row stride 256)
    int i = b * 256 + tid;
    if (i < N * 32) {
      size_t base = (size_t)i * 4;
      size_t row = base >> 7;
      int col = (int)(base & 127);
      const float4 v = *(const float4*)(x + base);
      ushort4 o = { f2bf(v.x), f2bf(v.y), f2bf(v.z), f2bf(v.w) };
      *(ushort4*)(comb + (row << 8) + col) = o;
    }
  } else if (b < nbx + nbz) {          // zero bucket totals
    int i = (b - nbx) * 256 + tid;
    if (i < nbkt) bktTotal[i] = 0u;
  } else {                             // W (128 x 256 f32) -> bf16
    int i = (b - nbx - nbz) * 256 + tid;
    if (i < 8192) {
      const float4 v = *(const float4*)(W + (size_t)i * 4);
      ushort4 o = { f2bf(v.x), f2bf(v.y), f2bf(v.z), f2bf(v.w) };
      *(ushort4*)(wbf + (size_t)i * 4) = o;
    }
  }
}

// ---------------- pass A1: per-block LDS histogram over buckets (dst>>8) ----------------
__global__ __launch_bounds__(256) void hist_k(const int* __restrict__ dst, int E,
                                              u32* __restrict__ bktTotal, int nbkt) {
  __shared__ u32 h[512];
  for (int t = threadIdx.x; t < 512; t += 256) h[t] = 0u;
  __syncthreads();
  int base = blockIdx.x * 4096;
  for (int it = 0; it < 16; it++) {
    int i = base + it * 256 + threadIdx.x;
    if (i < E) atomicAdd(&h[(u32)dst[i] >> 8], 1u);
  }
  __syncthreads();
  for (int t = threadIdx.x; t < nbkt; t += 256) {
    u32 c = h[t];
    if (c) atomicAdd(&bktTotal[t], c);
  }
}

// ---------------- bucket scan: starts, cursors, offsets[N] ----------------
__global__ __launch_bounds__(512) void bscan_k(const u32* __restrict__ bktTotal, int nbkt,
                                               int E, int N, u32* __restrict__ start,
                                               u32* __restrict__ cursor, u32* __restrict__ offsets) {
  __shared__ u32 s[512];
  int t = threadIdx.x;
  u32 v = (t < nbkt) ? bktTotal[t] : 0u;
  s[t] = v;
  __syncthreads();
  for (int off = 1; off < 512; off <<= 1) {
    u32 x = (t >= off) ? s[t - off] : 0u;
    __syncthreads();
    s[t] += x;
    __syncthreads();
  }
  u32 excl = s[t] - v;
  if (t < nbkt) { start[t] = excl; cursor[t] = excl; }
  if (t == nbkt - 1) start[nbkt] = excl + v;   // == E
  if (t == 0) offsets[N] = (u32)E;
}

// ---------------- pass A2: partition edges into bucket regions (packed u32) ----------------
__global__ __launch_bounds__(256) void part_k(const int* __restrict__ src, const int* __restrict__ dst,
                                              int E, u32* __restrict__ cursor,
                                              u32* __restrict__ packed, int nbkt) {
  __shared__ u32 h[512];
  for (int t = threadIdx.x; t < 512; t += 256) h[t] = 0u;
  __syncthreads();
  int base = blockIdx.x * 4096;
  for (int it = 0; it < 16; it++) {
    int i = base + it * 256 + threadIdx.x;
    if (i < E) atomicAdd(&h[(u32)dst[i] >> 8], 1u);
  }
  __syncthreads();
  for (int t = threadIdx.x; t < nbkt; t += 256) {
    u32 c = h[t];
    h[t] = c ? atomicAdd(&cursor[t], c) : 0u;   // reserve contiguous per-(block,bucket) range
  }
  __syncthreads();
  for (int it = 0; it < 16; it++) {
    int i = base + it * 256 + threadIdx.x;
    if (i < E) {
      u32 d = (u32)dst[i];
      u32 pos = atomicAdd(&h[d >> 8], 1u);      // LDS atomic
      packed[pos] = (u32)src[i] | ((d & 255u) << 24);
    }
  }
}

// ---------------- pass B: per-bucket counting sort -> offsets + ssrc ----------------
__global__ __launch_bounds__(256) void bucket_k(const u32* __restrict__ packed,
                                                const u32* __restrict__ start, int N,
                                                u32* __restrict__ offsets, int* __restrict__ ssrc) {
  __shared__ u32 cnt[256];
  __shared__ u32 scn[256];
  __shared__ u32 cur[256];
  int b = blockIdx.x, t = threadIdx.x;
  u32 lo = start[b], hi = start[b + 1];
  cnt[t] = 0u;
  __syncthreads();
  for (u32 j = lo + t; j < hi; j += 256) atomicAdd(&cnt[packed[j] >> 24], 1u);
  __syncthreads();
  u32 v = cnt[t];
  scn[t] = v;
  __syncthreads();
  for (int off = 1; off < 256; off <<= 1) {
    u32 x = (t >= off) ? scn[t - off] : 0u;
    __syncthreads();
    scn[t] += x;
    __syncthreads();
  }
  u32 base = lo + scn[t] - v;     // exclusive position of this node's segment
  int node = b * 256 + t;
  if (node < N) offsets[node] = base;
  cur[t] = base;
  __syncthreads();
  for (u32 j = lo + t; j < hi; j += 256) {
    u32 w = packed[j];
    u32 pos = atomicAdd(&cur[w >> 24], 1u);   // LDS atomic
    ssrc[pos] = (int)(w & 0xFFFFFFu);
  }
}

// ---------------- aggregate: one wave per node, 8 edges in flight ----------------
__global__ __launch_bounds__(256) void agg_k(const int* __restrict__ ssrc,
                                             const u32* __restrict__ offsets,
                                             u16* comb, int N) {
  int wid = (blockIdx.x * blockDim.x + threadIdx.x) >> 6;
  int lane = threadIdx.x & 63;
  if (wid >= N) return;
  int sub = lane >> 4;
  int cl = lane & 15;
  u32 s0 = offsets[wid], s1 = offsets[wid + 1];
  float a0=0.f,a1=0.f,a2=0.f,a3=0.f,a4=0.f,a5=0.f,a6=0.f,a7=0.f;
  u32 j = s0 + sub;
  for (; j + 4 < s1; j += 8) {
    int sA = ssrc[j];
    int sB = ssrc[j + 4];
    uint4 vA = *(const uint4*)(comb + ((size_t)sA << 8) + (cl << 3));
    uint4 vB = *(const uint4*)(comb + ((size_t)sB << 8) + (cl << 3));
    a0 += bflo(vA.x); a1 += bfhi(vA.x);
    a2 += bflo(vA.y); a3 += bfhi(vA.y);
    a4 += bflo(vA.z); a5 += bfhi(vA.z);
    a6 += bflo(vA.w); a7 += bfhi(vA.w);
    a0 += bflo(vB.x); a1 += bfhi(vB.x);
    a2 += bflo(vB.y); a3 += bfhi(vB.y);
    a4 += bflo(vB.z); a5 += bfhi(vB.z);
    a6 += bflo(vB.w); a7 += bfhi(vB.w);
  }
  if (j < s1) {
    int s = ssrc[j];
    uint4 v = *(const uint4*)(comb + ((size_t)s << 8) + (cl << 3));
    a0 += bflo(v.x); a1 += bfhi(v.x);
    a2 += bflo(v.y); a3 += bfhi(v.y);
    a4 += bflo(v.z); a5 += bfhi(v.z);
    a6 += bflo(v.w); a7 += bfhi(v.w);
  }
  a0 += __shfl_xor(a0, 16); a1 += __shfl_xor(a1, 16);
  a2 += __shfl_xor(a2, 16); a3 += __shfl_xor(a3, 16);
  a4 += __shfl_xor(a4, 16); a5 += __shfl_xor(a5, 16);
  a6 += __shfl_xor(a6, 16); a7 += __shfl_xor(a7, 16);
  a0 += __shfl_xor(a0, 32); a1 += __shfl_xor(a1, 32);
  a2 += __shfl_xor(a2, 32); a3 += __shfl_xor(a3, 32);
  a4 += __shfl_xor(a4, 32); a5 += __shfl_xor(a5, 32);
  a6 += __shfl_xor(a6, 32); a7 += __shfl_xor(a7, 32);
  if (sub == 0) {
    u32 deg = s1 - s0;
    float inv = 1.0f / (float)(deg > 0u ? deg : 1u);
    uint4 o;
    o.x = (u32)f2bf(a0 * inv) | ((u32)f2bf(a1 * inv) << 16);
    o.y = (u32)f2bf(a2 * inv) | ((u32)f2bf(a3 * inv) << 16);
    o.z = (u32)f2bf(a4 * inv) | ((u32)f2bf(a5 * inv) << 16);
    o.w = (u32)f2bf(a6 * inv) | ((u32)f2bf(a7 * inv) << 16);
    *(uint4*)(comb + ((size_t)wid << 8) + 128 + (cl << 3)) = o;
  }
}

// ---------------- GEMM: comb (N x 256 bf16) @ Wbf^T (+bias) -> out (N x 128 f32) ----------------
__global__ __launch_bounds__(256) void gemm_k(const u16* __restrict__ comb,
                                              const u16* __restrict__ wbf,
                                              const float* __restrict__ bias,
                                              float* __restrict__ out, int nstrips) {
  int wave = threadIdx.x >> 6, lane = threadIdx.x & 63;
  int strip = blockIdx.x * 4 + wave;
  if (strip >= nstrips) return;
  int la = lane & 15, lb = lane >> 4;

  const u16* abase = comb + ((size_t)(strip * 16 + la) << 8) + lb * 8;
  bf16x8 a[8];
#pragma unroll
  for (int kb = 0; kb < 8; kb++) a[kb] = *(const bf16x8*)(abase + kb * 32);

#pragma unroll
  for (int ct = 0; ct < 8; ct++) {
    f32x4 acc = { 0.f, 0.f, 0.f, 0.f };
    const u16* bbase = wbf + ((size_t)(ct * 16 + la) << 8) + lb * 8;
#pragma unroll
    for (int kb = 0; kb < 8; kb++) {
      bf16x8 b = *(const bf16x8*)(bbase + kb * 32);
      acc = __builtin_amdgcn_mfma_f32_16x16x32_bf16(a[kb], b, acc, 0, 0, 0);
    }
    float bc = bias[ct * 16 + la];
    int r0 = strip * 16 + lb * 4;
#pragma unroll
    for (int j = 0; j < 4; j++)
      out[((size_t)(r0 + j) << 7) + ct * 16 + la] = acc[j] + bc;
  }
}

extern "C" void kernel_launch(void* const* d_in, const int* in_sizes, int n_in,
                              void* d_out, int out_size, void* d_ws, size_t ws_size,
                              hipStream_t stream) {
  const float* x    = (const float*)d_in[0];
  const int*   ei   = (const int*)d_in[1];
  const float* W    = (const float*)d_in[2];
  const float* bias = (const float*)d_in[3];
  const int N = in_sizes[0] / 128;
  const int E = in_sizes[1] / 2;
  const int nbkt = (N + 255) >> 8;           // buckets of 256 nodes (<=512)
  const int* src = ei;
  const int* dst = ei + E;
  float* out = (float*)d_out;

  // transient CSR-build scratch in d_out (dead before gemm_k overwrites it):
  u32* packed   = (u32*)d_out;               // E   (src | (dst&255)<<24, bucket-partitioned)
  u32* bktTotal = packed + E;                // nbkt
  u32* start    = bktTotal + nbkt;           // nbkt+1
  u32* cursor   = start + nbkt + 1;          // nbkt

  char* ws = (char*)d_ws;
  u32* offsets = (u32*)ws;                   // N+1
  size_t off = ((size_t)(N + 1) * 4 + 255) & ~(size_t)255;
  int* ssrc = (int*)(ws + off);              // E
  off += (size_t)E * 4;
  off = (off + 255) & ~(size_t)255;
  u16* comb = (u16*)(ws + off);              // N*256 bf16 (x | mean)
  u16* wbf  = comb + (size_t)N * 256;        // 128*256 bf16

  const int nbx = (N * 32 + 255) / 256;
  const int nbz = (nbkt + 255) / 256;
  const int nba = (E + 4095) / 4096;
  pre_k<<<nbx + nbz + 32, 256, 0, stream>>>(x, comb, W, wbf, bktTotal, N, nbkt, nbx, nbz);
  hist_k<<<nba, 256, 0, stream>>>(dst, E, bktTotal, nbkt);
  bscan_k<<<1, 512, 0, stream>>>(bktTotal, nbkt, E, N, start, cursor, offsets);
  part_k<<<nba, 256, 0, stream>>>(src, dst, E, cursor, packed, nbkt);
  bucket_k<<<nbkt, 256, 0, stream>>>(packed, start, N, offsets, ssrc);
  agg_k<<<(N + 3) / 4, 256, 0, stream>>>(ssrc, offsets, comb, N);
  gemm_k<<<(N / 16 + 3) / 4, 256, 0, stream>>>(comb, wbf, bias, out, N / 16);
}

// Round 6
// 248.335 us; speedup vs baseline: 1.5157x; 1.1427x over previous
//
#include <hip/hip_runtime.h>

typedef unsigned int u32;
typedef unsigned short u16;
typedef __bf16 bf16x8 __attribute__((ext_vector_type(8)));
typedef float f32x4 __attribute__((ext_vector_type(4)));
typedef float f32x2 __attribute__((ext_vector_type(2)));

__device__ __forceinline__ u16 f2bf(float f) {
  u32 u = __builtin_bit_cast(u32, f);
  u32 r = (u + 0x7fffu + ((u >> 16) & 1u)) >> 16;   // RTNE
  return (u16)r;
}

// ---------------- fused pre-pass: conv x (bf16 + fp8) | zero bktTotal | conv W ----------------
__global__ __launch_bounds__(256) void pre_k(const float* __restrict__ x, u16* __restrict__ xbf,
                                             u32* __restrict__ xq,
                                             const float* __restrict__ W, u16* __restrict__ wbf,
                                             u32* __restrict__ bktTotal, int N, int nbkt,
                                             int nbx, int nbz) {
  int b = blockIdx.x, tid = threadIdx.x;
  if (b < nbx) {                       // x (N x 128 f32) -> xbf (bf16) + xq (fp8 e4m3, 4 packed/u32)
    int i = b * 256 + tid;             // i-th float4
    if (i < N * 32) {
      const float4 v = *(const float4*)(x + (size_t)i * 4);
      ushort4 o = { f2bf(v.x), f2bf(v.y), f2bf(v.z), f2bf(v.w) };
      *(ushort4*)(xbf + (size_t)i * 4) = o;
      u32 p = 0;
      p = __builtin_amdgcn_cvt_pk_fp8_f32(v.x, v.y, p, false);
      p = __builtin_amdgcn_cvt_pk_fp8_f32(v.z, v.w, p, true);
      xq[i] = p;
    }
  } else if (b < nbx + nbz) {          // zero bucket totals
    int i = (b - nbx) * 256 + tid;
    if (i < nbkt) bktTotal[i] = 0u;
  } else {                             // W (128 x 256 f32) -> bf16
    int i = (b - nbx - nbz) * 256 + tid;
    if (i < 8192) {
      const float4 v = *(const float4*)(W + (size_t)i * 4);
      ushort4 o = { f2bf(v.x), f2bf(v.y), f2bf(v.z), f2bf(v.w) };
      *(ushort4*)(wbf + (size_t)i * 4) = o;
    }
  }
}

// ---------------- pass A1: per-block LDS histogram over buckets (dst>>8) ----------------
__global__ __launch_bounds__(256) void hist_k(const int* __restrict__ dst, int E,
                                              u32* __restrict__ bktTotal, int nbkt) {
  __shared__ u32 h[512];
  for (int t = threadIdx.x; t < 512; t += 256) h[t] = 0u;
  __syncthreads();
  int base = blockIdx.x * 4096;
  for (int it = 0; it < 16; it++) {
    int i = base + it * 256 + threadIdx.x;
    if (i < E) atomicAdd(&h[(u32)dst[i] >> 8], 1u);
  }
  __syncthreads();
  for (int t = threadIdx.x; t < nbkt; t += 256) {
    u32 c = h[t];
    if (c) atomicAdd(&bktTotal[t], c);
  }
}

// ---------------- bucket scan: starts, cursors, offsets[N] ----------------
__global__ __launch_bounds__(512) void bscan_k(const u32* __restrict__ bktTotal, int nbkt,
                                               int E, int N, u32* __restrict__ start,
                                               u32* __restrict__ cursor, u32* __restrict__ offsets) {
  __shared__ u32 s[512];
  int t = threadIdx.x;
  u32 v = (t < nbkt) ? bktTotal[t] : 0u;
  s[t] = v;
  __syncthreads();
  for (int off = 1; off < 512; off <<= 1) {
    u32 x = (t >= off) ? s[t - off] : 0u;
    __syncthreads();
    s[t] += x;
    __syncthreads();
  }
  u32 excl = s[t] - v;
  if (t < nbkt) { start[t] = excl; cursor[t] = excl; }
  if (t == nbkt - 1) start[nbkt] = excl + v;   // == E
  if (t == 0) offsets[N] = (u32)E;
}

// ---------------- pass A2: partition edges into bucket regions (packed u32) ----------------
__global__ __launch_bounds__(256) void part_k(const int* __restrict__ src, const int* __restrict__ dst,
                                              int E, u32* __restrict__ cursor,
                                              u32* __restrict__ packed, int nbkt) {
  __shared__ u32 h[512];
  for (int t = threadIdx.x; t < 512; t += 256) h[t] = 0u;
  __syncthreads();
  int base = blockIdx.x * 4096;
  for (int it = 0; it < 16; it++) {
    int i = base + it * 256 + threadIdx.x;
    if (i < E) atomicAdd(&h[(u32)dst[i] >> 8], 1u);
  }
  __syncthreads();
  for (int t = threadIdx.x; t < nbkt; t += 256) {
    u32 c = h[t];
    h[t] = c ? atomicAdd(&cursor[t], c) : 0u;   // reserve contiguous per-(block,bucket) range
  }
  __syncthreads();
  for (int it = 0; it < 16; it++) {
    int i = base + it * 256 + threadIdx.x;
    if (i < E) {
      u32 d = (u32)dst[i];
      u32 pos = atomicAdd(&h[d >> 8], 1u);      // LDS atomic
      packed[pos] = (u32)src[i] | ((d & 255u) << 24);
    }
  }
}

// ---------------- pass B: per-bucket counting sort -> offsets + ssrc ----------------
__global__ __launch_bounds__(256) void bucket_k(const u32* __restrict__ packed,
                                                const u32* __restrict__ start, int N,
                                                u32* __restrict__ offsets, int* __restrict__ ssrc) {
  __shared__ u32 cnt[256];
  __shared__ u32 scn[256];
  __shared__ u32 cur[256];
  int b = blockIdx.x, t = threadIdx.x;
  u32 lo = start[b], hi = start[b + 1];
  cnt[t] = 0u;
  __syncthreads();
  for (u32 j = lo + t; j < hi; j += 256) atomicAdd(&cnt[packed[j] >> 24], 1u);
  __syncthreads();
  u32 v = cnt[t];
  scn[t] = v;
  __syncthreads();
  for (int off = 1; off < 256; off <<= 1) {
    u32 x = (t >= off) ? scn[t - off] : 0u;
    __syncthreads();
    scn[t] += x;
    __syncthreads();
  }
  u32 base = lo + scn[t] - v;     // exclusive position of this node's segment
  int node = b * 256 + t;
  if (node < N) offsets[node] = base;
  cur[t] = base;
  __syncthreads();
  for (u32 j = lo + t; j < hi; j += 256) {
    u32 w = packed[j];
    u32 pos = atomicAdd(&cur[w >> 24], 1u);   // LDS atomic
    ssrc[pos] = (int)(w & 0xFFFFFFu);
  }
}

// ---------------- fused aggregate + GEMM ----------------
// block = 4 waves = 64 nodes. Wave w: aggregate nodes [base+16w, base+16w+16) from fp8 table
// (means -> LDS as bf16), then MFMA its 16-row strip: A = [xbf rows | LDS means], B = wbf.
__global__ __launch_bounds__(256) void fuse_k(const int* __restrict__ ssrc,
                                              const u32* __restrict__ offsets,
                                              const u32* __restrict__ xq,
                                              const u16* __restrict__ xbf,
                                              const u16* __restrict__ wbf,
                                              const float* __restrict__ bias,
                                              float* __restrict__ out, int N) {
  __shared__ u16 mlds[64][136];               // padded stride vs bank conflicts
  int wv = threadIdx.x >> 6, lane = threadIdx.x & 63;
  int sub = lane >> 4, cl = lane & 15;
  int wbase = blockIdx.x * 64 + wv * 16;      // this wave's 16 nodes / strip rows

  // ---- phase 1: aggregate 16 nodes (4 edges in flight via sub, x2 unroll) ----
  for (int n = 0; n < 16; n++) {
    int node = wbase + n;
    if (node < N) {
      u32 s0 = offsets[node], s1 = offsets[node + 1];
      float a0=0.f,a1=0.f,a2=0.f,a3=0.f,a4=0.f,a5=0.f,a6=0.f,a7=0.f;
      u32 j = s0 + sub;
      for (; j + 4 < s1; j += 8) {
        int sA = ssrc[j];
        int sB = ssrc[j + 4];
        uint2 vA = *(const uint2*)(xq + ((size_t)sA << 5) + (cl << 1));
        uint2 vB = *(const uint2*)(xq + ((size_t)sB << 5) + (cl << 1));
        f32x2 p;
        p = __builtin_amdgcn_cvt_pk_f32_fp8(vA.x, false); a0 += p.x; a1 += p.y;
        p = __builtin_amdgcn_cvt_pk_f32_fp8(vA.x, true);  a2 += p.x; a3 += p.y;
        p = __builtin_amdgcn_cvt_pk_f32_fp8(vA.y, false); a4 += p.x; a5 += p.y;
        p = __builtin_amdgcn_cvt_pk_f32_fp8(vA.y, true);  a6 += p.x; a7 += p.y;
        p = __builtin_amdgcn_cvt_pk_f32_fp8(vB.x, false); a0 += p.x; a1 += p.y;
        p = __builtin_amdgcn_cvt_pk_f32_fp8(vB.x, true);  a2 += p.x; a3 += p.y;
        p = __builtin_amdgcn_cvt_pk_f32_fp8(vB.y, false); a4 += p.x; a5 += p.y;
        p = __builtin_amdgcn_cvt_pk_f32_fp8(vB.y, true);  a6 += p.x; a7 += p.y;
      }
      if (j < s1) {
        int s = ssrc[j];
        uint2 v = *(const uint2*)(xq + ((size_t)s << 5) + (cl << 1));
        f32x2 p;
        p = __builtin_amdgcn_cvt_pk_f32_fp8(v.x, false); a0 += p.x; a1 += p.y;
        p = __builtin_amdgcn_cvt_pk_f32_fp8(v.x, true);  a2 += p.x; a3 += p.y;
        p = __builtin_amdgcn_cvt_pk_f32_fp8(v.y, false); a4 += p.x; a5 += p.y;
        p = __builtin_amdgcn_cvt_pk_f32_fp8(v.y, true);  a6 += p.x; a7 += p.y;
      }
      a0 += __shfl_xor(a0, 16); a1 += __shfl_xor(a1, 16);
      a2 += __shfl_xor(a2, 16); a3 += __shfl_xor(a3, 16);
      a4 += __shfl_xor(a4, 16); a5 += __shfl_xor(a5, 16);
      a6 += __shfl_xor(a6, 16); a7 += __shfl_xor(a7, 16);
      a0 += __shfl_xor(a0, 32); a1 += __shfl_xor(a1, 32);
      a2 += __shfl_xor(a2, 32); a3 += __shfl_xor(a3, 32);
      a4 += __shfl_xor(a4, 32); a5 += __shfl_xor(a5, 32);
      a6 += __shfl_xor(a6, 32); a7 += __shfl_xor(a7, 32);
      if (sub == 0) {
        u32 deg = s1 - s0;
        float inv = 1.0f / (float)(deg > 0u ? deg : 1u);
        uint4 o;
        o.x = (u32)f2bf(a0 * inv) | ((u32)f2bf(a1 * inv) << 16);
        o.y = (u32)f2bf(a2 * inv) | ((u32)f2bf(a3 * inv) << 16);
        o.z = (u32)f2bf(a4 * inv) | ((u32)f2bf(a5 * inv) << 16);
        o.w = (u32)f2bf(a6 * inv) | ((u32)f2bf(a7 * inv) << 16);
        *(uint4*)&mlds[wv * 16 + n][cl * 8] = o;
      }
    }
  }
  __syncthreads();

  // ---- phase 2: 16-row GEMM strip (K=256: x from global, mean from LDS) ----
  int la = cl, lb = sub;
  bf16x8 a[8];
  const u16* ab = xbf + ((size_t)(wbase + la) << 7) + lb * 8;
#pragma unroll
  for (int kb = 0; kb < 4; kb++) a[kb] = *(const bf16x8*)(ab + kb * 32);
#pragma unroll
  for (int kb = 0; kb < 4; kb++) a[4 + kb] = *(const bf16x8*)(&mlds[wv * 16 + la][kb * 32 + lb * 8]);

#pragma unroll
  for (int ct = 0; ct < 8; ct++) {
    f32x4 acc = { 0.f, 0.f, 0.f, 0.f };
    const u16* bbase = wbf + ((size_t)(ct * 16 + la) << 8) + lb * 8;
#pragma unroll
    for (int kb = 0; kb < 8; kb++) {
      bf16x8 b = *(const bf16x8*)(bbase + kb * 32);
      acc = __builtin_amdgcn_mfma_f32_16x16x32_bf16(a[kb], b, acc, 0, 0, 0);
    }
    float bc = bias[ct * 16 + la];
#pragma unroll
    for (int j = 0; j < 4; j++) {
      int r = wbase + lb * 4 + j;
      if (r < N) out[((size_t)r << 7) + ct * 16 + la] = acc[j] + bc;
    }
  }
}

extern "C" void kernel_launch(void* const* d_in, const int* in_sizes, int n_in,
                              void* d_out, int out_size, void* d_ws, size_t ws_size,
                              hipStream_t stream) {
  const float* x    = (const float*)d_in[0];
  const int*   ei   = (const int*)d_in[1];
  const float* W    = (const float*)d_in[2];
  const float* bias = (const float*)d_in[3];
  const int N = in_sizes[0] / 128;
  const int E = in_sizes[1] / 2;
  const int nbkt = (N + 255) >> 8;           // buckets of 256 nodes
  const int* src = ei;
  const int* dst = ei + E;
  float* out = (float*)d_out;

  // transient CSR-build scratch in d_out (dead before fuse_k overwrites it):
  u32* packed   = (u32*)d_out;               // E   (src | (dst&255)<<24, bucket-partitioned)
  u32* bktTotal = packed + E;                // nbkt
  u32* start    = bktTotal + nbkt;           // nbkt+1
  u32* cursor   = start + nbkt + 1;          // nbkt

  char* ws = (char*)d_ws;
  u32* offsets = (u32*)ws;                   // N+1
  size_t off = ((size_t)(N + 1) * 4 + 255) & ~(size_t)255;
  int* ssrc = (int*)(ws + off);              // E
  off += (size_t)E * 4;
  off = (off + 255) & ~(size_t)255;
  u16* xbf = (u16*)(ws + off);               // N*128 bf16
  off += (size_t)N * 128 * 2;
  off = (off + 255) & ~(size_t)255;
  u32* xq = (u32*)(ws + off);                // N*32 u32 (N*128 fp8)
  off += (size_t)N * 128;
  off = (off + 255) & ~(size_t)255;
  u16* wbf = (u16*)(ws + off);               // 128*256 bf16

  const int nbx = (N * 32 + 255) / 256;
  const int nbz = (nbkt + 255) / 256;
  const int nba = (E + 4095) / 4096;
  pre_k<<<nbx + nbz + 32, 256, 0, stream>>>(x, xbf, xq, W, wbf, bktTotal, N, nbkt, nbx, nbz);
  hist_k<<<nba, 256, 0, stream>>>(dst, E, bktTotal, nbkt);
  bscan_k<<<1, 512, 0, stream>>>(bktTotal, nbkt, E, N, start, cursor, offsets);
  part_k<<<nba, 256, 0, stream>>>(src, dst, E, cursor, packed, nbkt);
  bucket_k<<<nbkt, 256, 0, stream>>>(packed, start, N, offsets, ssrc);
  fuse_k<<<(N + 63) / 64, 256, 0, stream>>>(ssrc, offsets, xq, xbf, wbf, bias, out, N);
}

// Round 7
// 211.883 us; speedup vs baseline: 1.7765x; 1.1720x over previous
//
#include <hip/hip_runtime.h>

typedef unsigned int u32;
typedef unsigned short u16;
typedef __bf16 bf16x8 __attribute__((ext_vector_type(8)));
typedef float f32x4 __attribute__((ext_vector_type(4)));
typedef float f32x2 __attribute__((ext_vector_type(2)));

__device__ __forceinline__ u16 f2bf(float f) {
  u32 u = __builtin_bit_cast(u32, f);
  u32 r = (u + 0x7fffu + ((u >> 16) & 1u)) >> 16;   // RTNE
  return (u16)r;
}

// ---------------- fused pre-pass: conv x (bf16 + fp8) | zero bktTotal | conv W ----------------
__global__ __launch_bounds__(256) void pre_k(const float* __restrict__ x, u16* __restrict__ xbf,
                                             u32* __restrict__ xq,
                                             const float* __restrict__ W, u16* __restrict__ wbf,
                                             u32* __restrict__ bktTotal, int N, int nbkt,
                                             int nbx, int nbz) {
  int b = blockIdx.x, tid = threadIdx.x;
  if (b < nbx) {                       // x (N x 128 f32) -> xbf (bf16) + xq (fp8 e4m3, 4 packed/u32)
    int i = b * 256 + tid;             // i-th float4
    if (i < N * 32) {
      const float4 v = *(const float4*)(x + (size_t)i * 4);
      ushort4 o = { f2bf(v.x), f2bf(v.y), f2bf(v.z), f2bf(v.w) };
      *(ushort4*)(xbf + (size_t)i * 4) = o;
      u32 p = 0;
      p = __builtin_amdgcn_cvt_pk_fp8_f32(v.x, v.y, p, false);
      p = __builtin_amdgcn_cvt_pk_fp8_f32(v.z, v.w, p, true);
      xq[i] = p;
    }
  } else if (b < nbx + nbz) {          // zero bucket totals
    int i = (b - nbx) * 256 + tid;
    if (i < nbkt) bktTotal[i] = 0u;
  } else {                             // W (128 x 256 f32) -> bf16
    int i = (b - nbx - nbz) * 256 + tid;
    if (i < 8192) {
      const float4 v = *(const float4*)(W + (size_t)i * 4);
      ushort4 o = { f2bf(v.x), f2bf(v.y), f2bf(v.z), f2bf(v.w) };
      *(ushort4*)(wbf + (size_t)i * 4) = o;
    }
  }
}

// ---------------- pass A1: per-block LDS histogram over buckets (dst>>8) ----------------
__global__ __launch_bounds__(256) void hist_k(const int* __restrict__ dst, int E,
                                              u32* __restrict__ bktTotal, int nbkt) {
  __shared__ u32 h[512];
  for (int t = threadIdx.x; t < 512; t += 256) h[t] = 0u;
  __syncthreads();
  int base = blockIdx.x * 8192;
  for (int it = 0; it < 32; it++) {
    int i = base + it * 256 + threadIdx.x;
    if (i < E) atomicAdd(&h[(u32)dst[i] >> 8], 1u);
  }
  __syncthreads();
  for (int t = threadIdx.x; t < nbkt; t += 256) {
    u32 c = h[t];
    if (c) atomicAdd(&bktTotal[t], c);
  }
}

// ---------------- bucket scan: starts, cursors, offsets[N] ----------------
__global__ __launch_bounds__(512) void bscan_k(const u32* __restrict__ bktTotal, int nbkt,
                                               int E, int N, u32* __restrict__ start,
                                               u32* __restrict__ cursor, u32* __restrict__ offsets) {
  __shared__ u32 s[512];
  int t = threadIdx.x;
  u32 v = (t < nbkt) ? bktTotal[t] : 0u;
  s[t] = v;
  __syncthreads();
  for (int off = 1; off < 512; off <<= 1) {
    u32 x = (t >= off) ? s[t - off] : 0u;
    __syncthreads();
    s[t] += x;
    __syncthreads();
  }
  u32 excl = s[t] - v;
  if (t < nbkt) { start[t] = excl; cursor[t] = excl; }
  if (t == nbkt - 1) start[nbkt] = excl + v;   // == E
  if (t == 0) offsets[N] = (u32)E;
}

// ---------------- pass A2: partition edges into bucket regions (packed u32) ----------------
__global__ __launch_bounds__(256) void part_k(const int* __restrict__ src, const int* __restrict__ dst,
                                              int E, u32* __restrict__ cursor,
                                              u32* __restrict__ packed, int nbkt) {
  __shared__ u32 h[512];
  for (int t = threadIdx.x; t < 512; t += 256) h[t] = 0u;
  __syncthreads();
  int base = blockIdx.x * 8192;
  for (int it = 0; it < 32; it++) {
    int i = base + it * 256 + threadIdx.x;
    if (i < E) atomicAdd(&h[(u32)dst[i] >> 8], 1u);
  }
  __syncthreads();
  for (int t = threadIdx.x; t < nbkt; t += 256) {
    u32 c = h[t];
    h[t] = c ? atomicAdd(&cursor[t], c) : 0u;   // reserve contiguous per-(block,bucket) range
  }
  __syncthreads();
  for (int it = 0; it < 32; it++) {
    int i = base + it * 256 + threadIdx.x;
    if (i < E) {
      u32 d = (u32)dst[i];
      u32 pos = atomicAdd(&h[d >> 8], 1u);      // LDS atomic
      packed[pos] = (u32)src[i] | ((d & 255u) << 24);
    }
  }
}

// ---------------- pass B: per-bucket counting sort -> offsets + ssrc ----------------
__global__ __launch_bounds__(256) void bucket_k(const u32* __restrict__ packed,
                                                const u32* __restrict__ start, int N,
                                                u32* __restrict__ offsets, int* __restrict__ ssrc) {
  __shared__ u32 cnt[256];
  __shared__ u32 scn[256];
  __shared__ u32 cur[256];
  int b = blockIdx.x, t = threadIdx.x;
  u32 lo = start[b], hi = start[b + 1];
  cnt[t] = 0u;
  __syncthreads();
  for (u32 j = lo + t; j < hi; j += 256) atomicAdd(&cnt[packed[j] >> 24], 1u);
  __syncthreads();
  u32 v = cnt[t];
  scn[t] = v;
  __syncthreads();
  for (int off = 1; off < 256; off <<= 1) {
    u32 x = (t >= off) ? scn[t - off] : 0u;
    __syncthreads();
    scn[t] += x;
    __syncthreads();
  }
  u32 base = lo + scn[t] - v;     // exclusive position of this node's segment
  int node = b * 256 + t;
  if (node < N) offsets[node] = base;
  cur[t] = base;
  __syncthreads();
  for (u32 j = lo + t; j < hi; j += 256) {
    u32 w = packed[j];
    u32 pos = atomicAdd(&cur[w >> 24], 1u);   // LDS atomic
    ssrc[pos] = (int)(w & 0xFFFFFFu);
  }
}

// ---------------- fused aggregate + GEMM ----------------
// block = 4 waves = 64 nodes. Phase 1: each 16-lane sub-group owns one node
// (lane cl holds features [8cl, 8cl+8) of the fp8 row) -> 4 nodes/wave concurrently,
// 4-deep edge unroll = 16 gathers in flight, NO cross-lane reduction.
// Phase 2: 16-row MFMA strip per wave: A = [xbf rows | LDS means], B = wbf.
#define DEC8(vv) { f32x2 p;                                             \
    p = __builtin_amdgcn_cvt_pk_f32_fp8((vv).x, false); a0 += p.x; a1 += p.y; \
    p = __builtin_amdgcn_cvt_pk_f32_fp8((vv).x, true);  a2 += p.x; a3 += p.y; \
    p = __builtin_amdgcn_cvt_pk_f32_fp8((vv).y, false); a4 += p.x; a5 += p.y; \
    p = __builtin_amdgcn_cvt_pk_f32_fp8((vv).y, true);  a6 += p.x; a7 += p.y; }

__global__ __launch_bounds__(256) void fuse_k(const int* __restrict__ ssrc,
                                              const u32* __restrict__ offsets,
                                              const u32* __restrict__ xq,
                                              const u16* __restrict__ xbf,
                                              const u16* __restrict__ wbf,
                                              const float* __restrict__ bias,
                                              float* __restrict__ out, int N) {
  __shared__ u16 mlds[64][136];               // padded stride vs bank conflicts
  int wv = threadIdx.x >> 6, lane = threadIdx.x & 63;
  int sub = lane >> 4, cl = lane & 15;
  int wbase = blockIdx.x * 64 + wv * 16;      // this wave's 16 nodes / strip rows

  // ---- phase 1: 4 rounds x 4 concurrent nodes ----
  for (int r = 0; r < 4; r++) {
    int ln = r * 4 + sub;                     // local row in strip [0,16)
    int node = wbase + ln;
    float a0=0.f,a1=0.f,a2=0.f,a3=0.f,a4=0.f,a5=0.f,a6=0.f,a7=0.f;
    u32 deg = 0;
    if (node < N) {
      u32 s0 = offsets[node], s1 = offsets[node + 1];
      deg = s1 - s0;
      u32 j = s0;
      for (; j + 3 < s1; j += 4) {
        int e0 = ssrc[j], e1 = ssrc[j + 1], e2 = ssrc[j + 2], e3 = ssrc[j + 3];
        uint2 v0 = *(const uint2*)(xq + ((size_t)e0 << 5) + (cl << 1));
        uint2 v1 = *(const uint2*)(xq + ((size_t)e1 << 5) + (cl << 1));
        uint2 v2 = *(const uint2*)(xq + ((size_t)e2 << 5) + (cl << 1));
        uint2 v3 = *(const uint2*)(xq + ((size_t)e3 << 5) + (cl << 1));
        DEC8(v0) DEC8(v1) DEC8(v2) DEC8(v3)
      }
      for (; j < s1; j++) {
        int e = ssrc[j];
        uint2 v = *(const uint2*)(xq + ((size_t)e << 5) + (cl << 1));
        DEC8(v)
      }
    }
    float inv = 1.0f / (float)(deg ? deg : 1u);
    uint4 o;
    o.x = (u32)f2bf(a0 * inv) | ((u32)f2bf(a1 * inv) << 16);
    o.y = (u32)f2bf(a2 * inv) | ((u32)f2bf(a3 * inv) << 16);
    o.z = (u32)f2bf(a4 * inv) | ((u32)f2bf(a5 * inv) << 16);
    o.w = (u32)f2bf(a6 * inv) | ((u32)f2bf(a7 * inv) << 16);
    *(uint4*)&mlds[wv * 16 + ln][cl * 8] = o;   // 16 lanes cover all 128 feats
  }
  __syncthreads();

  // ---- phase 2: 16-row GEMM strip (K=256: x from global, mean from LDS) ----
  int la = cl, lb = sub;
  bf16x8 a[8];
  const u16* ab = xbf + ((size_t)(wbase + la) << 7) + lb * 8;
#pragma unroll
  for (int kb = 0; kb < 4; kb++) a[kb] = *(const bf16x8*)(ab + kb * 32);
#pragma unroll
  for (int kb = 0; kb < 4; kb++) a[4 + kb] = *(const bf16x8*)(&mlds[wv * 16 + la][kb * 32 + lb * 8]);

#pragma unroll
  for (int ct = 0; ct < 8; ct++) {
    f32x4 acc = { 0.f, 0.f, 0.f, 0.f };
    const u16* bbase = wbf + ((size_t)(ct * 16 + la) << 8) + lb * 8;
#pragma unroll
    for (int kb = 0; kb < 8; kb++) {
      bf16x8 b = *(const bf16x8*)(bbase + kb * 32);
      acc = __builtin_amdgcn_mfma_f32_16x16x32_bf16(a[kb], b, acc, 0, 0, 0);
    }
    float bc = bias[ct * 16 + la];
#pragma unroll
    for (int j = 0; j < 4; j++) {
      int r = wbase + lb * 4 + j;
      if (r < N) out[((size_t)r << 7) + ct * 16 + la] = acc[j] + bc;
    }
  }
}

extern "C" void kernel_launch(void* const* d_in, const int* in_sizes, int n_in,
                              void* d_out, int out_size, void* d_ws, size_t ws_size,
                              hipStream_t stream) {
  const float* x    = (const float*)d_in[0];
  const int*   ei   = (const int*)d_in[1];
  const float* W    = (const float*)d_in[2];
  const float* bias = (const float*)d_in[3];
  const int N = in_sizes[0] / 128;
  const int E = in_sizes[1] / 2;
  const int nbkt = (N + 255) >> 8;           // buckets of 256 nodes
  const int* src = ei;
  const int* dst = ei + E;
  float* out = (float*)d_out;

  // transient CSR-build scratch in d_out (dead before fuse_k overwrites it):
  u32* packed   = (u32*)d_out;               // E   (src | (dst&255)<<24, bucket-partitioned)
  u32* bktTotal = packed + E;                // nbkt
  u32* start    = bktTotal + nbkt;           // nbkt+1
  u32* cursor   = start + nbkt + 1;          // nbkt

  char* ws = (char*)d_ws;
  u32* offsets = (u32*)ws;                   // N+1
  size_t off = ((size_t)(N + 1) * 4 + 255) & ~(size_t)255;
  int* ssrc = (int*)(ws + off);              // E
  off += (size_t)E * 4;
  off = (off + 255) & ~(size_t)255;
  u16* xbf = (u16*)(ws + off);               // N*128 bf16
  off += (size_t)N * 128 * 2;
  off = (off + 255) & ~(size_t)255;
  u32* xq = (u32*)(ws + off);                // N*32 u32 (N*128 fp8)
  off += (size_t)N * 128;
  off = (off + 255) & ~(size_t)255;
  u16* wbf = (u16*)(ws + off);               // 128*256 bf16

  const int nbx = (N * 32 + 255) / 256;
  const int nbz = (nbkt + 255) / 256;
  const int nba = (E + 8191) / 8192;
  pre_k<<<nbx + nbz + 32, 256, 0, stream>>>(x, xbf, xq, W, wbf, bktTotal, N, nbkt, nbx, nbz);
  hist_k<<<nba, 256, 0, stream>>>(dst, E, bktTotal, nbkt);
  bscan_k<<<1, 512, 0, stream>>>(bktTotal, nbkt, E, N, start, cursor, offsets);
  part_k<<<nba, 256, 0, stream>>>(src, dst, E, cursor, packed, nbkt);
  bucket_k<<<nbkt, 256, 0, stream>>>(packed, start, N, offsets, ssrc);
  fuse_k<<<(N + 63) / 64, 256, 0, stream>>>(ssrc, offsets, xq, xbf, wbf, bias, out, N);
}